// Round 1
// baseline (296.722 us; speedup 1.0000x reference)
//
#include <hip/hip_runtime.h>

// AttentionHead: B=4, S=2048, D=1024, fp32 in/out, bf16 MFMA compute.
// Pipeline: cvt X->bf16 ; W^T bf16 ; Q/K/V projections (GEMM) ; V^T ;
//           per-2-batch { scores=QK^T (triangular) ; causal softmax ; O=PV }.

typedef __attribute__((ext_vector_type(8))) short short8;
typedef __attribute__((ext_vector_type(4))) float floatx4;

#define BM 128
#define BN 128
#define BKK 32

__device__ __forceinline__ unsigned short f2b(float f) {
  unsigned u = __builtin_bit_cast(unsigned, f);
  u = (u + 0x7fffu + ((u >> 16) & 1u)) >> 16;
  return (unsigned short)u;
}

__device__ __forceinline__ void gload_lds16(const unsigned short* gsrc, unsigned short* ldst) {
  __builtin_amdgcn_global_load_lds(
      (const __attribute__((address_space(1))) unsigned int*)gsrc,
      (__attribute__((address_space(3))) unsigned int*)ldst,
      16, 0, 0);
}

// MODE 0: plain grid (x=M-tiles, y=N-tiles), bf16 output.
// MODE 1: triangular grid (x=tri-index, y=batch), fp32 output, scaled.
// MODE 2: plain grid + batch z, K limited to (bi+1)*BM (causal PV), fp32 output.
template <int MODE>
__global__ __launch_bounds__(256) void gemm_bt(
    const unsigned short* __restrict__ A,
    const unsigned short* __restrict__ Bt,
    void* __restrict__ Cv,
    int K, int lda, int ldb, int ldc, float scale,
    long long sA, long long sB, long long sC) {
  int bi, bj, bz;
  if constexpr (MODE == 1) {
    int t = blockIdx.x;
    bi = 0;
    while ((bi + 1) * (bi + 2) / 2 <= t) ++bi;
    bj = t - bi * (bi + 1) / 2;
    bz = blockIdx.y;
  } else {
    bi = blockIdx.x; bj = blockIdx.y; bz = blockIdx.z;
  }
  A  += (long long)bz * sA;
  Bt += (long long)bz * sB;

  int Keff = K;
  if constexpr (MODE == 2) {
    int kl = (bi + 1) * BM;
    if (kl < Keff) Keff = kl;
  }

  __shared__ unsigned short lA[BM * BKK];
  __shared__ unsigned short lB[BN * BKK];

  const int t = threadIdx.x;
  const int wave = t >> 6, lane = t & 63;
  const int wr = wave >> 1, wc = wave & 1;  // 2x2 waves, each owns 64x64 out

  // staging: per K-step each wave issues 2+2 global_load_lds_dwordx4
  const int srow = wave * 32 + (lane >> 2);
  const int scol = (lane & 3) * 8;
  const unsigned short* gA = A + (long long)(bi * BM + srow) * lda + scol;
  const unsigned short* gB = Bt + (long long)(bj * BN + srow) * ldb + scol;
  unsigned short* lAw = lA + wave * 1024;  // wave-uniform LDS dest (HW adds lane*16B)
  unsigned short* lBw = lB + wave * 1024;

  floatx4 acc[4][4] = {};
  const int frow = lane & 15;
  const int kg = (lane >> 4) * 8;

  for (int k0 = 0; k0 < Keff; k0 += BKK) {
    __syncthreads();
    gload_lds16(gA + k0, lAw);
    gload_lds16(gA + k0 + 16 * lda, lAw + 512);
    gload_lds16(gB + k0, lBw);
    gload_lds16(gB + k0 + 16 * ldb, lBw + 512);
    __syncthreads();
    short8 af[4], bf[4];
#pragma unroll
    for (int m = 0; m < 4; ++m)
      af[m] = *(const short8*)&lA[(wr * 64 + m * 16 + frow) * BKK + kg];
#pragma unroll
    for (int n = 0; n < 4; ++n)
      bf[n] = *(const short8*)&lB[(wc * 64 + n * 16 + frow) * BKK + kg];
#pragma unroll
    for (int m = 0; m < 4; ++m)
#pragma unroll
      for (int n = 0; n < 4; ++n)
        acc[m][n] = __builtin_amdgcn_mfma_f32_16x16x32_bf16(af[m], bf[n], acc[m][n], 0, 0, 0);
  }

  // C/D layout: col = lane&15, row = (lane>>4)*4 + j   [m89-verified]
  const long long crow0 = (long long)bi * BM + wr * 64 + ((lane >> 4) * 4);
  const int ccol = bj * BN + wc * 64 + (lane & 15);
  if constexpr (MODE == 0) {
    unsigned short* C = (unsigned short*)Cv + (long long)bz * sC;
#pragma unroll
    for (int m = 0; m < 4; ++m)
#pragma unroll
      for (int j = 0; j < 4; ++j) {
        unsigned short* cp = C + (crow0 + m * 16 + j) * ldc + ccol;
#pragma unroll
        for (int n = 0; n < 4; ++n) cp[n * 16] = f2b(acc[m][n][j] * scale);
      }
  } else {
    float* C = (float*)Cv + (long long)bz * sC;
#pragma unroll
    for (int m = 0; m < 4; ++m)
#pragma unroll
      for (int j = 0; j < 4; ++j) {
        float* cp = C + (crow0 + m * 16 + j) * ldc + ccol;
#pragma unroll
        for (int n = 0; n < 4; ++n) cp[n * 16] = acc[m][n][j] * scale;
      }
  }
}

__global__ __launch_bounds__(256) void cvt_f32_bf16(
    const float* __restrict__ in, unsigned short* __restrict__ out, int n4) {
  int idx = blockIdx.x * 256 + threadIdx.x;
  const int stride = gridDim.x * 256;
  for (int i = idx; i < n4; i += stride) {
    float4 x = ((const float4*)in)[i];
    ushort4 o;
    o.x = f2b(x.x); o.y = f2b(x.y); o.z = f2b(x.z); o.w = f2b(x.w);
    ((ushort4*)out)[i] = o;
  }
}

// W [1024][1024] fp32 (i,o) -> Wt bf16 [o][i], one W per blockIdx.z
__global__ __launch_bounds__(256) void wcvt_t(
    const float* __restrict__ W0, const float* __restrict__ W1,
    const float* __restrict__ W2, unsigned short* __restrict__ Wt) {
  const float* W = blockIdx.z == 0 ? W0 : (blockIdx.z == 1 ? W1 : W2);
  unsigned short* dst = Wt + (long long)blockIdx.z * 1048576LL;
  __shared__ unsigned short tile[64][65];
  const int t = threadIdx.x;
  const int i0 = blockIdx.x * 64, j0 = blockIdx.y * 64;
#pragma unroll
  for (int r = 0; r < 16; ++r) {
    int lin = r * 256 + t;
    int i = lin >> 6, j = lin & 63;
    tile[i][j] = f2b(W[(long long)(i0 + i) * 1024 + j0 + j]);
  }
  __syncthreads();
#pragma unroll
  for (int r = 0; r < 16; ++r) {
    int lin = r * 256 + t;
    int o = lin >> 6, i = lin & 63;
    dst[(long long)(j0 + o) * 1024 + i0 + i] = tile[i][o];
  }
}

// bf16 [R][C] -> [C][R] per batch z
__global__ __launch_bounds__(256) void transpose_bf16k(
    const unsigned short* __restrict__ in, unsigned short* __restrict__ out,
    int R, int Cc, long long ibs, long long obs) {
  __shared__ unsigned short tile[64][65];
  const int t = threadIdx.x;
  const int i0 = blockIdx.x * 64, j0 = blockIdx.y * 64;
  const unsigned short* src = in + (long long)blockIdx.z * ibs;
  unsigned short* dst = out + (long long)blockIdx.z * obs;
#pragma unroll
  for (int r = 0; r < 16; ++r) {
    int lin = r * 256 + t;
    int i = lin >> 6, j = lin & 63;
    tile[i][j] = src[(long long)(i0 + i) * Cc + j0 + j];
  }
  __syncthreads();
#pragma unroll
  for (int r = 0; r < 16; ++r) {
    int lin = r * 256 + t;
    int j = lin >> 6, i = lin & 63;
    dst[(long long)(j0 + j) * R + i0 + i] = tile[i][j];
  }
}

// One wave per 2048-wide row; causal mask by index; writes FULL row (zeros past q).
__global__ __launch_bounds__(256) void softmax_causal(
    const float* __restrict__ Sb, unsigned short* __restrict__ P) {
  const int row = blockIdx.x * 4 + (threadIdx.x >> 6);
  const int lane = threadIdx.x & 63;
  const int q = row & 2047;
  const float4* src = (const float4*)(Sb + (long long)row * 2048);
  float v[32];
#pragma unroll
  for (int g = 0; g < 8; ++g) {
    float4 x = src[g * 64 + lane];
    const int c0 = g * 256 + lane * 4;
    v[g * 4 + 0] = (c0 + 0 <= q) ? x.x : -1e30f;
    v[g * 4 + 1] = (c0 + 1 <= q) ? x.y : -1e30f;
    v[g * 4 + 2] = (c0 + 2 <= q) ? x.z : -1e30f;
    v[g * 4 + 3] = (c0 + 3 <= q) ? x.w : -1e30f;
  }
  float mx = -1e30f;
#pragma unroll
  for (int i = 0; i < 32; ++i) mx = fmaxf(mx, v[i]);
  for (int off = 32; off; off >>= 1) mx = fmaxf(mx, __shfl_xor(mx, off));
  float s = 0.f;
#pragma unroll
  for (int i = 0; i < 32; ++i) {
    float e = (v[i] > -1e29f) ? __expf(v[i] - mx) : 0.f;
    v[i] = e; s += e;
  }
  for (int off = 32; off; off >>= 1) s += __shfl_xor(s, off);
  const float inv = 1.f / s;
  ushort4* dst = (ushort4*)(P + (long long)row * 2048);
#pragma unroll
  for (int g = 0; g < 8; ++g) {
    ushort4 o;
    o.x = f2b(v[g * 4 + 0] * inv);
    o.y = f2b(v[g * 4 + 1] * inv);
    o.z = f2b(v[g * 4 + 2] * inv);
    o.w = f2b(v[g * 4 + 3] * inv);
    dst[g * 64 + lane] = o;
  }
}

extern "C" void kernel_launch(void* const* d_in, const int* in_sizes, int n_in,
                              void* d_out, int out_size, void* d_ws, size_t ws_size,
                              hipStream_t stream) {
  const float* Xk = (const float*)d_in[0];
  const float* Xv = (const float*)d_in[1];
  const float* Xq = (const float*)d_in[2];
  const float* Wk = (const float*)d_in[3];
  const float* Wv = (const float*)d_in[4];
  const float* Wq = (const float*)d_in[5];
  float* out = (float*)d_out;

  const long long XE = 8388608LL;   // 4*2048*1024
  const long long WE = 1048576LL;   // 1024*1024
  const long long SE2 = 4194304LL;  // 2048*2048

  // ws layout (ushort elems): Wt[3*WE] | Xb[3*XE] | Kb | Vb | Qb | Vt  (~124 MB)
  unsigned short* ws = (unsigned short*)d_ws;
  unsigned short* Wt = ws;
  unsigned short* Xb = ws + 3 * WE;
  unsigned short* Kb = Xb + 3 * XE;
  unsigned short* Vb = Kb + XE;
  unsigned short* Qb = Vb + XE;
  unsigned short* Vt = Qb + XE;
  // After projections Xb is dead: reuse for 2-batch score (fp32) + P (bf16) buffers.
  float* Sbuf = (float*)Xb;                          // 2*SE2 floats (32 MB)
  unsigned short* Pbuf = Xb + 4 * SE2;               // 2*SE2 ushorts (16 MB)

  cvt_f32_bf16<<<2048, 256, 0, stream>>>(Xk, Xb, (int)(XE / 4));
  cvt_f32_bf16<<<2048, 256, 0, stream>>>(Xv, Xb + XE, (int)(XE / 4));
  cvt_f32_bf16<<<2048, 256, 0, stream>>>(Xq, Xb + 2 * XE, (int)(XE / 4));
  wcvt_t<<<dim3(16, 16, 3), 256, 0, stream>>>(Wk, Wv, Wq, Wt);

  // projections: [8192x1024] @ [1024x1024] -> bf16
  gemm_bt<0><<<dim3(64, 8, 1), 256, 0, stream>>>(Xb, Wt, (void*)Kb,
      1024, 1024, 1024, 1024, 1.f, 0, 0, 0);
  gemm_bt<0><<<dim3(64, 8, 1), 256, 0, stream>>>(Xb + XE, Wt + WE, (void*)Vb,
      1024, 1024, 1024, 1024, 1.f, 0, 0, 0);
  gemm_bt<0><<<dim3(64, 8, 1), 256, 0, stream>>>(Xb + 2 * XE, Wt + 2 * WE, (void*)Qb,
      1024, 1024, 1024, 1024, 1.f, 0, 0, 0);

  // V [b][2048][1024] -> Vt [b][1024][2048]
  transpose_bf16k<<<dim3(32, 16, 4), 256, 0, stream>>>(Vb, Vt, 2048, 1024,
      2048LL * 1024, 1024LL * 2048);

  for (int ch = 0; ch < 2; ++ch) {
    const unsigned short* Qc = Qb + (long long)ch * 2 * 2048 * 1024;
    const unsigned short* Kc = Kb + (long long)ch * 2 * 2048 * 1024;
    // scores = Q K^T / 32, lower-triangular tiles only (136 per batch)
    gemm_bt<1><<<dim3(136, 2, 1), 256, 0, stream>>>(Qc, Kc, (void*)Sbuf,
        1024, 1024, 1024, 2048, 0.03125f, 2048LL * 1024, 2048LL * 1024, SE2);
    softmax_causal<<<1024, 256, 0, stream>>>(Sbuf, Pbuf);
    // O = P V  (K limited to (bi+1)*128 per row-tile)
    gemm_bt<2><<<dim3(16, 8, 2), 256, 0, stream>>>(Pbuf,
        Vt + (long long)ch * 2 * 1024 * 2048,
        (void*)(out + (long long)ch * 2 * 2048 * 1024),
        2048, 2048, 2048, 1024, 1.f, SE2, 1024LL * 2048, 2048LL * 1024);
  }
}

// Round 2
// 189.594 us; speedup vs baseline: 1.5650x; 1.5650x over previous
//
#include <hip/hip_runtime.h>

// AttentionHead: B=4, S=2048, D=1024, fp32 in/out, bf16 MFMA compute.
// cvt X->bf16 ; W^T bf16 ; fused {K,V^T,Q} projections ; scores=QK^T (tri, all b) ;
// causal softmax (P bf16 in-place over S) ; O=PV (causal K-limit).

typedef __attribute__((ext_vector_type(8))) short short8;
typedef __attribute__((ext_vector_type(4))) float floatx4;

static constexpr long long XE = 8388608LL;  // 4*2048*1024 elems
static constexpr long long WE = 1048576LL;  // 1024*1024 elems

static __device__ __forceinline__ unsigned short f2b(float f) {
  unsigned u = __builtin_bit_cast(unsigned, f);
  u = (u + 0x7fffu + ((u >> 16) & 1u)) >> 16;
  return (unsigned short)u;
}

static __device__ __forceinline__ void gload16(const unsigned short* g, unsigned short* l) {
  __builtin_amdgcn_global_load_lds(
      (const __attribute__((address_space(1))) unsigned int*)g,
      (__attribute__((address_space(3))) unsigned int*)l, 16, 0, 0);
}

// 128x128 tile, BK=64, 4 waves (2x2), 4x4 16x16x32 bf16 frags.
// LDS tile [row][8 chunks of 16B]; LDS[row][c] holds global chunk c^(row&7)
// (staged via pre-swizzled global source; linear global_load_lds dest).
template <bool BF16OUT>
static __device__ __forceinline__ void gemm_core(
    const unsigned short* __restrict__ A, const unsigned short* __restrict__ Bt,
    int lda, int ldb, int nk, void* __restrict__ Cv, int ldc, float scale,
    int bi, int bj) {
  __shared__ __align__(16) unsigned short lA[128 * 64];
  __shared__ __align__(16) unsigned short lB[128 * 64];
  const int t = threadIdx.x, wave = t >> 6, lane = t & 63;
  const int wr = wave >> 1, wc = wave & 1;
  const int sr = lane >> 3;              // row within 8-row group
  const int sc = ((lane & 7) ^ sr) * 8;  // swizzled source chunk (elements)
  const unsigned short* gA = A + (long long)(bi * 128 + wave * 32 + sr) * lda + sc;
  const unsigned short* gB = Bt + (long long)(bj * 128 + wave * 32 + sr) * ldb + sc;
  unsigned short* lAw = lA + wave * 2048;
  unsigned short* lBw = lB + wave * 2048;
  const int frow = lane & 15, hi = lane >> 4;

  floatx4 acc[4][4] = {};
  for (int ks = 0; ks < nk; ++ks) {
    const long long k0 = (long long)ks * 64;
    __syncthreads();
#pragma unroll
    for (int g = 0; g < 4; ++g) {
      gload16(gA + (long long)g * 8 * lda + k0, lAw + g * 512);
      gload16(gB + (long long)g * 8 * ldb + k0, lBw + g * 512);
    }
    __syncthreads();
#pragma unroll
    for (int kk = 0; kk < 2; ++kk) {
      const int ch = (kk * 4 + hi) ^ (frow & 7);  // read-side inverse swizzle
      short8 af[4], bf[4];
#pragma unroll
      for (int m = 0; m < 4; ++m)
        af[m] = *(const short8*)&lA[(wr * 64 + m * 16 + frow) * 64 + ch * 8];
#pragma unroll
      for (int n = 0; n < 4; ++n)
        bf[n] = *(const short8*)&lB[(wc * 64 + n * 16 + frow) * 64 + ch * 8];
#pragma unroll
      for (int m = 0; m < 4; ++m)
#pragma unroll
        for (int n = 0; n < 4; ++n)
          acc[m][n] = __builtin_amdgcn_mfma_f32_16x16x32_bf16(af[m], bf[n], acc[m][n], 0, 0, 0);
    }
  }

  // C/D: col = lane&15, row = (lane>>4)*4 + j
  const long long crow0 = (long long)bi * 128 + wr * 64 + hi * 4;
  const int ccol = bj * 128 + wc * 64 + frow;
  if constexpr (BF16OUT) {
    unsigned short* C = (unsigned short*)Cv;
#pragma unroll
    for (int m = 0; m < 4; ++m)
#pragma unroll
      for (int j = 0; j < 4; ++j) {
        unsigned short* cp = C + (crow0 + m * 16 + j) * (long long)ldc + ccol;
#pragma unroll
        for (int n = 0; n < 4; ++n) cp[n * 16] = f2b(acc[m][n][j] * scale);
      }
  } else {
    float* C = (float*)Cv;
#pragma unroll
    for (int m = 0; m < 4; ++m)
#pragma unroll
      for (int j = 0; j < 4; ++j) {
        float* cp = C + (crow0 + m * 16 + j) * (long long)ldc + ccol;
#pragma unroll
        for (int n = 0; n < 4; ++n) cp[n * 16] = acc[m][n][j] * scale;
      }
  }
}

// z=0: K = Xk@Wk ; z=1: V^T = (Wv^T)(Xv^T) via operand swap ; z=2: Q = Xq@Wq
__global__ __launch_bounds__(256) void proj_kernel(
    const unsigned short* __restrict__ Xb, const unsigned short* __restrict__ Wt,
    unsigned short* __restrict__ Kb, unsigned short* __restrict__ Vt,
    unsigned short* __restrict__ Qb) {
  const int z = blockIdx.z;
  const unsigned short* A;
  const unsigned short* B;
  unsigned short* C;
  int ldc, bi, bj;
  if (z == 1) {
    A = Wt + WE; B = Xb + XE; C = Vt; ldc = 8192;
    bi = blockIdx.y; bj = blockIdx.x;           // M=1024 (o), N=8192 (b*s)
  } else {
    A = Xb + (z ? 2 * XE : 0); B = Wt + (z ? 2 * WE : 0);
    C = z ? Qb : Kb; ldc = 1024;
    bi = blockIdx.x; bj = blockIdx.y;           // M=8192, N=1024
  }
  gemm_core<true>(A, B, 1024, 1024, 16, C, ldc, 1.f, bi, bj);
}

// lower-triangular tiles, all 4 batches: grid (136, 4)
__global__ __launch_bounds__(256) void scores_kernel(
    const unsigned short* __restrict__ Qb, const unsigned short* __restrict__ Kb,
    float* __restrict__ S) {
  int t = blockIdx.x, bi = 0;
  while ((bi + 1) * (bi + 2) / 2 <= t) ++bi;
  const int bj = t - bi * (bi + 1) / 2;
  const long long b = blockIdx.y;
  gemm_core<false>(Qb + b * 2048 * 1024, Kb + b * 2048 * 1024, 1024, 1024, 16,
                   S + b * 2048 * 2048, 2048, 0.03125f, bi, bj);
}

// O = P V ; P in-place over S (lda 4096 ushorts), K limited to (bi+1)*128.
// grid (32,16): x = bj + 8*b, y -> bi = 15-y (heavy first, batches interleaved).
__global__ __launch_bounds__(256) void pv_kernel(
    const unsigned short* __restrict__ P, const unsigned short* __restrict__ Vt,
    float* __restrict__ out) {
  const int b = blockIdx.x >> 3, bj = blockIdx.x & 7;
  const int bi = 15 - blockIdx.y;
  gemm_core<false>(P + (long long)b * 2048 * 4096, Vt + (long long)b * 2048,
                   4096, 8192, (bi + 1) * 2,
                   out + (long long)b * 2048 * 1024, 1024, 1.f, bi, bj);
}

// fused fp32->bf16 convert of the three activations: grid (1024, 3)
__global__ __launch_bounds__(256) void cvt3(
    const float* __restrict__ X0, const float* __restrict__ X1,
    const float* __restrict__ X2, unsigned short* __restrict__ Xb) {
  const float* in = blockIdx.y == 0 ? X0 : (blockIdx.y == 1 ? X1 : X2);
  unsigned short* out = Xb + (long long)blockIdx.y * XE;
  const int n4 = (int)(XE / 4);
  const int stride = 1024 * 256;
  for (int i = blockIdx.x * 256 + threadIdx.x; i < n4; i += stride) {
    float4 x = ((const float4*)in)[i];
    ushort4 o;
    o.x = f2b(x.x); o.y = f2b(x.y); o.z = f2b(x.z); o.w = f2b(x.w);
    ((ushort4*)out)[i] = o;
  }
}

// W [1024][1024] fp32 (i,o) -> Wt bf16 [o][i]
__global__ __launch_bounds__(256) void wcvt_t(
    const float* __restrict__ W0, const float* __restrict__ W1,
    const float* __restrict__ W2, unsigned short* __restrict__ Wt) {
  const float* W = blockIdx.z == 0 ? W0 : (blockIdx.z == 1 ? W1 : W2);
  unsigned short* dst = Wt + (long long)blockIdx.z * WE;
  __shared__ unsigned short tile[64][65];
  const int t = threadIdx.x;
  const int i0 = blockIdx.x * 64, j0 = blockIdx.y * 64;
#pragma unroll
  for (int r = 0; r < 16; ++r) {
    int lin = r * 256 + t;
    int i = lin >> 6, j = lin & 63;
    tile[i][j] = f2b(W[(long long)(i0 + i) * 1024 + j0 + j]);
  }
  __syncthreads();
#pragma unroll
  for (int r = 0; r < 16; ++r) {
    int lin = r * 256 + t;
    int o = lin >> 6, i = lin & 63;
    dst[(long long)(j0 + o) * 1024 + i0 + i] = tile[i][o];
  }
}

// one wave per row; reads fp32 row, writes bf16 P in-place over the row's
// first half (race-free: each wave touches only its own row). grid 2048.
__global__ __launch_bounds__(256) void softmax_causal(float* __restrict__ Sb) {
  const int row = blockIdx.x * 4 + (threadIdx.x >> 6);
  const int lane = threadIdx.x & 63;
  const int q = row & 2047;
  const float4* src = (const float4*)(Sb + (long long)row * 2048);
  float v[32];
#pragma unroll
  for (int g = 0; g < 8; ++g) {
    float4 x = src[g * 64 + lane];
    const int c0 = g * 256 + lane * 4;
    v[g * 4 + 0] = (c0 + 0 <= q) ? x.x : -1e30f;
    v[g * 4 + 1] = (c0 + 1 <= q) ? x.y : -1e30f;
    v[g * 4 + 2] = (c0 + 2 <= q) ? x.z : -1e30f;
    v[g * 4 + 3] = (c0 + 3 <= q) ? x.w : -1e30f;
  }
  float mx = -1e30f;
#pragma unroll
  for (int i = 0; i < 32; ++i) mx = fmaxf(mx, v[i]);
  for (int off = 32; off; off >>= 1) mx = fmaxf(mx, __shfl_xor(mx, off));
  float s = 0.f;
#pragma unroll
  for (int i = 0; i < 32; ++i) {
    float e = (v[i] > -1e29f) ? __expf(v[i] - mx) : 0.f;
    v[i] = e; s += e;
  }
  for (int off = 32; off; off >>= 1) s += __shfl_xor(s, off);
  const float inv = 1.f / s;
  asm volatile("" ::: "memory");  // fence loads (fp32) before aliased stores (bf16)
  unsigned short* dst = (unsigned short*)Sb + (long long)row * 4096;
#pragma unroll
  for (int g = 0; g < 8; ++g) {
    ushort4 o;
    o.x = f2b(v[g * 4 + 0] * inv);
    o.y = f2b(v[g * 4 + 1] * inv);
    o.z = f2b(v[g * 4 + 2] * inv);
    o.w = f2b(v[g * 4 + 3] * inv);
    ((ushort4*)dst)[g * 64 + lane] = o;
  }
}

extern "C" void kernel_launch(void* const* d_in, const int* in_sizes, int n_in,
                              void* d_out, int out_size, void* d_ws, size_t ws_size,
                              hipStream_t stream) {
  const float* Xk = (const float*)d_in[0];
  const float* Xv = (const float*)d_in[1];
  const float* Xq = (const float*)d_in[2];
  const float* Wk = (const float*)d_in[3];
  const float* Wv = (const float*)d_in[4];
  const float* Wq = (const float*)d_in[5];
  float* out = (float*)d_out;

  // ws (ushort elems): S region [0, 33.5M) fp32 4*2048*2048, aliased by
  // Wt[0,3WE) + Xb[3WE, 3WE+3XE) which die before scores writes S.
  // Then Qb | Kb | Vt. Peak = 33554432 + 3*XE = 58.7M ushorts = 117.4 MB.
  unsigned short* ws = (unsigned short*)d_ws;
  float* S = (float*)d_ws;
  unsigned short* Wt = ws;
  unsigned short* Xb = ws + 3 * WE;
  unsigned short* Qb = ws + 33554432LL;
  unsigned short* Kb = Qb + XE;
  unsigned short* Vt = Kb + XE;

  cvt3<<<dim3(1024, 3), 256, 0, stream>>>(Xk, Xv, Xq, Xb);
  wcvt_t<<<dim3(16, 16, 3), 256, 0, stream>>>(Wk, Wv, Wq, Wt);

  // fused projections: z=0 K (64x8), z=1 V^T (64x8 swapped), z=2 Q (64x8)
  proj_kernel<<<dim3(64, 8, 3), 256, 0, stream>>>(Xb, Wt, Kb, Vt, Qb);

  // scores = Q K^T / 32, triangular tiles, all batches
  scores_kernel<<<dim3(136, 4), 256, 0, stream>>>(Qb, Kb, S);

  // softmax + bf16 P in-place
  softmax_causal<<<2048, 256, 0, stream>>>(S);

  // O = P V
  pv_kernel<<<dim3(32, 16), 256, 0, stream>>>((const unsigned short*)d_ws, Vt, out);
}